// Round 3
// baseline (115.670 us; speedup 1.0000x reference)
//
#include <hip/hip_runtime.h>
#include <math.h>

#define N_ 8192
#define P_ 512

typedef __fp16 half8  __attribute__((ext_vector_type(8)));
typedef __fp16 half2t __attribute__((ext_vector_type(2)));
typedef float  floatx16 __attribute__((ext_vector_type(16)));

union H8 { half8 v; half2t h2[4]; };

static __device__ __forceinline__ half2t pk2(float a, float b) {
    return __builtin_amdgcn_cvt_pkrtz(a, b);
}

// LDS region0 (bytes):
//   phase A: bpS 512 rows x 48 halfs (96 B/row) = 49152 @0
//   phase C: g1S (32x264 halfs = 16896) @0 ; hpS (32x33 f32 = 4224) @17408 ;
//            xS (32x25 f32 = 3200) @21760 ; accS (32x256 f32 = 32768) @25088
#define HP_OFF  17408
#define XS_OFF  21760
#define ACC_OFF 25088
#define REG0_SZ 57856

// 256 blocks x 1024 thr (16 waves), 1 block/CU, 4 waves/SIMD.
// The 268 MB poison fill between iterations evicts L2+L3, so phase-B/C
// weight reads are ~900-cyc cold HBM misses issued behind barriers where
// every wave stalls together. The p-loop has NO vmem ops, so loads issued
// before it stay in flight for free. Strategy: register-prefetch the
// phase-B scalars + GEMM2 first K-batch before phase A; issue the GEMM1
// weights + GEMM2 second K-batch right after the p-loop (>=3 barriers
// before use). Plain global loads only (no global_load_lds).
__global__ __launch_bounds__(1024, 4) void k_fused(
    const float* __restrict__ r,
    const float* __restrict__ rp,
    const float* __restrict__ coeff_x,
    const float* __restrict__ coeff_y,
    const float* __restrict__ Wa1,
    const float* __restrict__ Wa2,
    const float* __restrict__ Wa3,
    const float* __restrict__ Wp1,
    const float* __restrict__ bp1,
    const float* __restrict__ Wp2,
    const float* __restrict__ bp2,
    const float* __restrict__ Wg1,
    const float* __restrict__ bg1,
    const float* __restrict__ Wg2,
    const float* __restrict__ bg2,
    const float* __restrict__ Wg3,
    const float* __restrict__ bg3,
    float* __restrict__ out)
{
    __shared__ __align__(16) unsigned char reg0[REG0_SZ];
    __shared__ __align__(16) float4 cyS[512];
    __shared__ float sA[16][32];         // also reused as redS
    __shared__ float aoA[4][16][32];
    __shared__ float aoS[32][4];

    const int tid  = threadIdx.x;
    const int n0   = blockIdx.x * 32;
    const int lane = tid & 63;
    const int wv   = tid >> 6;           // 16 waves
    const int j32  = lane & 31;
    const int hl   = lane >> 5;
    const int k0g  = hl * 8;

    // GEMM2 geometry (needed for prefetch indices)
    const int gg   = wv >> 3;            // wave group: K [gg*128, gg*128+128)
    const int wv8  = wv & 7;
    const int jc   = (wv8 << 5) + j32;   // output column 0..255
    const int B0   = gg << 7;

    // -------- cold-HBM register prefetch #1 (issued before phase A) ------
    float xpre = 0.f;
    if (tid < 256) {
        const int nn = tid >> 3, k = tid & 7;
        xpre = (k < 4) ? r[(n0+nn)*4 + k] : rp[(n0+nn)*4 + k - 4];
    }
    const int iB = tid >> 5;             // 0..31
    const float wpb  = bp1[iB];
    const float wp0  = Wp1[iB],      wp1v = Wp1[32+iB];
    const float wp2v = Wp1[64+iB],   wp3v = Wp1[96+iB];
    const float bp2v = bp2[iB & 15];     // == bp2[i2] when tid<512
    const float bg2v = bg2[jc];
    const float w3v  = Wg3[jc];
    const float bg3v = bg3[0];
    // GEMM2 first K-batch (q=0,1): 16 f32 regs, live across the p-loop.
    float wg2f[16];
#pragma unroll
    for (int q = 0; q < 2; ++q) {
#pragma unroll
        for (int t = 0; t < 4; ++t) {
            const int kb = B0 + q*16 + hl*8 + 2*t;
            wg2f[q*8 + 2*t]     = Wg2[kb*256 + jc];
            wg2f[q*8 + 2*t + 1] = Wg2[(kb+1)*256 + jc];
        }
    }

    // ================= Phase A: attention =================
    if (tid < 512) {
        const float2 cx = ((const float2*)coeff_x)[tid];
        half2t* wrow = (half2t*)(reg0 + tid * 96);
#pragma unroll
        for (int q = 0; q < 16; ++q) {
            const float b0 = cx.x * Wa1[64 + 2*q]     + cx.y * Wa1[96 + 2*q];
            const float b1 = cx.x * Wa1[64 + 2*q + 1] + cx.y * Wa1[96 + 2*q + 1];
            wrow[q] = pk2(b0, b1);
        }
        cyS[tid] = ((const float4*)coeff_y)[tid];
    }

    H8 anh1, anh2;
    {
        const float2 rv = ((const float2*)r)[2 * (n0 + j32)];
#pragma unroll
        for (int q = 0; q < 4; ++q) {
            const int k1 = k0g + 2*q, k2 = 16 + k0g + 2*q;
            anh1.h2[q] = pk2(rv.x*Wa1[k1]   + rv.y*Wa1[32+k1],
                             rv.x*Wa1[k1+1] + rv.y*Wa1[32+k1+1]);
            anh2.h2[q] = pk2(rv.x*Wa1[k2]   + rv.y*Wa1[32+k2],
                             rv.x*Wa1[k2+1] + rv.y*Wa1[32+k2+1]);
        }
    }
    H8 af1, af2;
#pragma unroll
    for (int q = 0; q < 4; ++q) {
        af1.h2[q] = pk2(Wa2[(k0g + 2*q)     * 32 + j32],
                        Wa2[(k0g + 2*q + 1) * 32 + j32]);
        af2.h2[q] = pk2(Wa2[(16 + k0g + 2*q)     * 32 + j32],
                        Wa2[(16 + k0g + 2*q + 1) * 32 + j32]);
    }
    half2t w3h[8];
#pragma unroll
    for (int q = 0; q < 8; ++q) {
        const int r0 = ((2*q) & 3) + 8*(q >> 1) + 4*hl;
        w3h[q] = pk2(Wa3[r0], Wa3[r0 + 1]);
    }

    __syncthreads();

    const half2t zero2 = pk2(0.f, 0.f);
    float s = 0.0f, aox = 0.f, aoy = 0.f, aoz = 0.f, aow = 0.f;

#pragma unroll 2
    for (int pl = 0; pl < 32; ++pl) {
        const int ploc = wv * 32 + pl;
        const half2t* rowq = (const half2t*)(reg0 + ploc * 96) + hl * 4;

        H8 bf1, bf2;
#pragma unroll
        for (int q = 0; q < 4; ++q) {
            bf1.h2[q] = __builtin_elementwise_max(anh1.h2[q] + rowq[q],     zero2);
            bf2.h2[q] = __builtin_elementwise_max(anh2.h2[q] + rowq[8 + q], zero2);
        }

        floatx16 zc = {};
        floatx16 acc = __builtin_amdgcn_mfma_f32_32x32x16_f16(af1.v, bf1.v, zc, 0, 0, 0);
        acc = __builtin_amdgcn_mfma_f32_32x32x16_f16(af2.v, bf2.v, acc, 0, 0, 0);

        float d0, d1, d2, d3;
        {
            half2t z0 = __builtin_elementwise_max(pk2(acc[0],  acc[1]),  zero2);
            half2t z1 = __builtin_elementwise_max(pk2(acc[2],  acc[3]),  zero2);
            half2t z2 = __builtin_elementwise_max(pk2(acc[4],  acc[5]),  zero2);
            half2t z3 = __builtin_elementwise_max(pk2(acc[6],  acc[7]),  zero2);
            half2t z4 = __builtin_elementwise_max(pk2(acc[8],  acc[9]),  zero2);
            half2t z5 = __builtin_elementwise_max(pk2(acc[10], acc[11]), zero2);
            half2t z6 = __builtin_elementwise_max(pk2(acc[12], acc[13]), zero2);
            half2t z7 = __builtin_elementwise_max(pk2(acc[14], acc[15]), zero2);
            d0 = __builtin_amdgcn_fdot2(z1, w3h[1], __builtin_amdgcn_fdot2(z0, w3h[0], 0.f, false), false);
            d1 = __builtin_amdgcn_fdot2(z3, w3h[3], __builtin_amdgcn_fdot2(z2, w3h[2], 0.f, false), false);
            d2 = __builtin_amdgcn_fdot2(z5, w3h[5], __builtin_amdgcn_fdot2(z4, w3h[4], 0.f, false), false);
            d3 = __builtin_amdgcn_fdot2(z7, w3h[7], __builtin_amdgcn_fdot2(z6, w3h[6], 0.f, false), false);
        }
        float dot = (d0 + d1) + (d2 + d3);
        dot += __shfl_xor(dot, 32);

        const float e = __expf(dot);   // logits ~N(0,1.3): no-max-sub safe
        const float4 cyv = cyS[ploc];
        s   += e;
        aox += e * cyv.x;
        aoy += e * cyv.y;
        aoz += e * cyv.z;
        aow += e * cyv.w;
    }

    // -------- cold-HBM prefetch #2: pack Wg2 q=0,1 (frees 16 f32 regs),
    // issue GEMM2 q=2,3 + GEMM1 weights; >=3 barriers before use ---------
    H8 wB01[2];
#pragma unroll
    for (int q = 0; q < 2; ++q)
#pragma unroll
        for (int t = 0; t < 4; ++t)
            wB01[q].h2[t] = pk2(wg2f[q*8 + 2*t], wg2f[q*8 + 2*t + 1]);

    float wg2g[16];
#pragma unroll
    for (int q = 2; q < 4; ++q) {
#pragma unroll
        for (int t = 0; t < 4; ++t) {
            const int kb = B0 + q*16 + hl*8 + 2*t;
            wg2g[(q-2)*8 + 2*t]     = Wg2[kb*256 + jc];
            wg2g[(q-2)*8 + 2*t + 1] = Wg2[(kb+1)*256 + jc];
        }
    }

    const int jcol = (wv << 5) + j32;    // GEMM1 column (waves 0..7)
    float wg1f[8], wg1g[8];
    float bg1v = 0.f;
    if (wv < 8) {
        bg1v = bg1[jcol];
#pragma unroll
        for (int q = 0; q < 4; ++q) {
            wg1f[2*q]   = Wg1[(k0g + 2*q)*256 + jcol];
            wg1f[2*q+1] = Wg1[(k0g + 2*q + 1)*256 + jcol];
        }
        if (hl == 0) {
#pragma unroll
            for (int q = 0; q < 4; ++q) {
                wg1g[2*q]   = Wg1[(16 + 2*q)*256 + jcol];
                wg1g[2*q+1] = Wg1[(17 + 2*q)*256 + jcol];
            }
        }
    }

    if (lane < 32) {
        sA[wv][lane]      = s;
        aoA[0][wv][lane]  = aox;
        aoA[1][wv][lane]  = aoy;
        aoA[2][wv][lane]  = aoz;
        aoA[3][wv][lane]  = aow;
    }
    __syncthreads();

    if (tid < 32) {
        float S = 0.f, A0 = 0.f, A1 = 0.f, A2 = 0.f, A3 = 0.f;
#pragma unroll
        for (int w = 0; w < 16; ++w) {
            S  += sA[w][tid];
            A0 += aoA[0][w][tid];
            A1 += aoA[1][w][tid];
            A2 += aoA[2][w][tid];
            A3 += aoA[3][w][tid];
        }
        const float inv = 1.0f / S;
        aoS[tid][0] = A0 * inv;
        aoS[tid][1] = A1 * inv;
        aoS[tid][2] = A2 * inv;
        aoS[tid][3] = A3 * inv;
    }
    __syncthreads();

    // ================= Phase B: c-MLP + x assembly =================
    float* hpS = (float*)(reg0 + HP_OFF);
    float* xS  = (float*)(reg0 + XS_OFF);
    const int nB = tid & 31;

    if (tid < 256) {
        const int nn = tid >> 3, k = tid & 7;
        xS[nn*25 + k] = xpre;
    }
    {
        const float a0 = aoS[nB][0], a1 = aoS[nB][1], a2 = aoS[nB][2], a3 = aoS[nB][3];
        float a = wpb + a0*wp0 + a1*wp1v + a2*wp2v + a3*wp3v;
        hpS[nB*33 + iB] = fmaxf(a, 0.0f);
    }
    __syncthreads();

    if (tid < 512) {
        const int i2 = tid >> 5;         // 0..15  (== iB here)
        float a = bp2v;
#pragma unroll
        for (int i = 0; i < 32; ++i) a += hpS[nB*33 + i] * Wp2[i*16 + i2];
        xS[nB*25 + 8 + i2] = a;
    }
    __syncthreads();

    // ================= Phase C: g-network via MFMA =================
    __fp16* g1S = (__fp16*)reg0;

    // GEMM1: g1 = relu(x @ Wg1 + bg1), K=24 padded to 32 (waves 0..7)
    if (wv < 8) {
        H8 xa1, xa2, wb1, wb2;
        const float* xrow = xS + j32 * 25;
#pragma unroll
        for (int q = 0; q < 4; ++q) {
            xa1.h2[q] = pk2(xrow[k0g + 2*q], xrow[k0g + 2*q + 1]);
            wb1.h2[q] = pk2(wg1f[2*q], wg1f[2*q+1]);
            if (hl == 0) {
                xa2.h2[q] = pk2(xrow[16 + 2*q], xrow[16 + 2*q + 1]);
                wb2.h2[q] = pk2(wg1g[2*q], wg1g[2*q+1]);
            } else {
                xa2.h2[q] = pk2(0.f, 0.f);
                wb2.h2[q] = pk2(0.f, 0.f);
            }
        }
        floatx16 g1acc = {};
        g1acc = __builtin_amdgcn_mfma_f32_32x32x16_f16(xa1.v, wb1.v, g1acc, 0, 0, 0);
        g1acc = __builtin_amdgcn_mfma_f32_32x32x16_f16(xa2.v, wb2.v, g1acc, 0, 0, 0);

#pragma unroll
        for (int i = 0; i < 16; ++i) {
            const int row = (i & 3) + 8*(i >> 2) + 4*hl;
            g1S[row*264 + jcol] = (__fp16)fmaxf(g1acc[i] + bg1v, 0.0f);
        }
    }
    __syncthreads();

    // GEMM2: g2 = relu(g1 @ Wg2 + bg2); dot Wg3; exp.
    // K=256 split across wave groups: gg handles K [gg*128, gg*128+128).
    // q=0..3 of the first c-batch come from register prefetch.
    {
        float* accS = (float*)(reg0 + ACC_OFF);
        float* redS = &sA[0][0];

        floatx16 acc2 = {};
        const __fp16* arow = g1S + j32 * 264 + B0;

        H8 wB[4], wBn[4];
        wB[0] = wB01[0];
        wB[1] = wB01[1];
#pragma unroll
        for (int q = 2; q < 4; ++q)
#pragma unroll
            for (int t = 0; t < 4; ++t)
                wB[q].h2[t] = pk2(wg2g[(q-2)*8 + 2*t], wg2g[(q-2)*8 + 2*t + 1]);

#pragma unroll
        for (int c = 0; c < 2; ++c) {
            if (c == 0) {
#pragma unroll
                for (int q = 0; q < 4; ++q) {
                    const int kb = B0 + 64 + q*16 + hl*8;
#pragma unroll
                    for (int t = 0; t < 4; ++t)
                        wBn[q].h2[t] = pk2(Wg2[(kb + 2*t)*256 + jc],
                                           Wg2[(kb + 2*t + 1)*256 + jc]);
                }
            }
#pragma unroll
            for (int q = 0; q < 4; ++q) {
                H8 af;
                af.v = *(const half8*)(arow + c*64 + q*16 + hl*8);
                acc2 = __builtin_amdgcn_mfma_f32_32x32x16_f16(af.v, wB[q].v, acc2, 0, 0, 0);
            }
#pragma unroll
            for (int q = 0; q < 4; ++q) wB[q] = wBn[q];
        }

        if (gg == 1) {
#pragma unroll
            for (int i = 0; i < 16; ++i) {
                const int row = (i & 3) + 8*(i >> 2) + 4*hl;
                accS[row*256 + jc] = acc2[i];
            }
        }
        __syncthreads();

        if (gg == 0) {
            float part[16];
#pragma unroll
            for (int i = 0; i < 16; ++i) {
                const int row = (i & 3) + 8*(i >> 2) + 4*hl;
                part[i] = fmaxf(acc2[i] + accS[row*256 + jc] + bg2v, 0.0f) * w3v;
            }
#pragma unroll
            for (int off = 1; off <= 16; off <<= 1) {
#pragma unroll
                for (int i = 0; i < 16; ++i) part[i] += __shfl_xor(part[i], off);
            }
            if ((lane & 31) == 0) {
#pragma unroll
                for (int i = 0; i < 16; ++i) {
                    const int row = (i & 3) + 8*(i >> 2) + 4*hl;
                    redS[wv8*32 + row] = part[i];
                }
            }
        }
        __syncthreads();

        if (tid < 32) {
            float v = bg3v;
#pragma unroll
            for (int w = 0; w < 8; ++w) v += redS[w*32 + tid];
            out[n0 + tid] = __expf(v);
        }
    }
}

extern "C" void kernel_launch(void* const* d_in, const int* in_sizes, int n_in,
                              void* d_out, int out_size, void* d_ws, size_t ws_size,
                              hipStream_t stream)
{
    const float* r   = (const float*)d_in[0];
    const float* rp  = (const float*)d_in[1];
    const float* cx  = (const float*)d_in[2];
    const float* cy  = (const float*)d_in[3];
    const float* Wa1 = (const float*)d_in[4];
    const float* Wa2 = (const float*)d_in[5];
    const float* Wa3 = (const float*)d_in[6];
    const float* Wp1 = (const float*)d_in[7];
    const float* bp1 = (const float*)d_in[8];
    const float* Wp2 = (const float*)d_in[9];
    const float* bp2 = (const float*)d_in[10];
    const float* Wg1 = (const float*)d_in[11];
    const float* bg1 = (const float*)d_in[12];
    const float* Wg2 = (const float*)d_in[13];
    const float* bg2 = (const float*)d_in[14];
    const float* Wg3 = (const float*)d_in[15];
    const float* bg3 = (const float*)d_in[16];

    hipLaunchKernelGGL(k_fused, dim3(N_/32), dim3(1024), 0, stream,
                       r, rp, cx, cy, Wa1, Wa2, Wa3, Wp1, bp1, Wp2, bp2,
                       Wg1, bg1, Wg2, bg2, Wg3, bg3, (float*)d_out);
}

// Round 4
// 108.553 us; speedup vs baseline: 1.0656x; 1.0656x over previous
//
#include <hip/hip_runtime.h>
#include <math.h>

#define N_ 8192
#define P_ 512

typedef __fp16 half8  __attribute__((ext_vector_type(8)));
typedef __fp16 half2t __attribute__((ext_vector_type(2)));
typedef float  floatx16 __attribute__((ext_vector_type(16)));

union H8 { half8 v; half2t h2[4]; };

static __device__ __forceinline__ half2t pk2(float a, float b) {
    return __builtin_amdgcn_cvt_pkrtz(a, b);
}

// LDS region0 (bytes):
//   phase A: bpS 512 rows x 48 halfs (96 B/row) = 49152
//   phase C: g1S (32x264 halfs = 16896) @0 ; hpS (32x33 f32 = 4224) @17408 ;
//            xS (32x25 f32 = 3200) @21760
#define HP_OFF 17408
#define XS_OFF 21760

// 256 blocks x 512 thr (measured-best base, 110.2-111.7us).
// Only change vs that base: POST-p-loop register prefetch of all phase-B/C
// weights. The 268MB poison fill evicts L2+L3 each iteration, so those
// reads are ~900-cyc cold HBM misses otherwise issued right behind
// barriers where every wave stalls together. Issued after the p-loop they
// hide under sA-write + softmax reduce + phase B (>=3 barriers). No
// register lives across the p-loop (round-3 lesson: that risks spills
// under the 128-VGPR cap).
__global__ __launch_bounds__(512, 4) void k_fused(
    const float* __restrict__ r,
    const float* __restrict__ rp,
    const float* __restrict__ coeff_x,
    const float* __restrict__ coeff_y,
    const float* __restrict__ Wa1,
    const float* __restrict__ Wa2,
    const float* __restrict__ Wa3,
    const float* __restrict__ Wp1,
    const float* __restrict__ bp1,
    const float* __restrict__ Wp2,
    const float* __restrict__ bp2,
    const float* __restrict__ Wg1,
    const float* __restrict__ bg1,
    const float* __restrict__ Wg2,
    const float* __restrict__ bg2,
    const float* __restrict__ Wg3,
    const float* __restrict__ bg3,
    float* __restrict__ out)
{
    __shared__ __align__(16) unsigned char reg0[49152];
    __shared__ __align__(16) float4 cyS[512];
    __shared__ float sA[8][32];          // also reused as redS
    __shared__ float aoA[4][8][32];
    __shared__ float aoS[32][4];

    const int tid  = threadIdx.x;
    const int n0   = blockIdx.x * 32;
    const int lane = tid & 63;
    const int wv   = tid >> 6;           // 8 waves
    const int j32  = lane & 31;
    const int hl   = lane >> 5;
    const int k0g  = hl * 8;

    // ================= Phase A: attention =================
    {
        const float2 cx = ((const float2*)coeff_x)[tid];
        half2t* wrow = (half2t*)(reg0 + tid * 96);
#pragma unroll
        for (int q = 0; q < 16; ++q) {
            const float b0 = cx.x * Wa1[64 + 2*q]     + cx.y * Wa1[96 + 2*q];
            const float b1 = cx.x * Wa1[64 + 2*q + 1] + cx.y * Wa1[96 + 2*q + 1];
            wrow[q] = pk2(b0, b1);
        }
        cyS[tid] = ((const float4*)coeff_y)[tid];
    }

    H8 anh1, anh2;
    {
        const float2 rv = ((const float2*)r)[2 * (n0 + j32)];
#pragma unroll
        for (int q = 0; q < 4; ++q) {
            const int k1 = k0g + 2*q, k2 = 16 + k0g + 2*q;
            anh1.h2[q] = pk2(rv.x*Wa1[k1]   + rv.y*Wa1[32+k1],
                             rv.x*Wa1[k1+1] + rv.y*Wa1[32+k1+1]);
            anh2.h2[q] = pk2(rv.x*Wa1[k2]   + rv.y*Wa1[32+k2],
                             rv.x*Wa1[k2+1] + rv.y*Wa1[32+k2+1]);
        }
    }
    H8 af1, af2;
#pragma unroll
    for (int q = 0; q < 4; ++q) {
        af1.h2[q] = pk2(Wa2[(k0g + 2*q)     * 32 + j32],
                        Wa2[(k0g + 2*q + 1) * 32 + j32]);
        af2.h2[q] = pk2(Wa2[(16 + k0g + 2*q)     * 32 + j32],
                        Wa2[(16 + k0g + 2*q + 1) * 32 + j32]);
    }
    half2t w3h[8];
#pragma unroll
    for (int q = 0; q < 8; ++q) {
        const int r0 = ((2*q) & 3) + 8*(q >> 1) + 4*hl;
        w3h[q] = pk2(Wa3[r0], Wa3[r0 + 1]);
    }

    __syncthreads();

    const half2t zero2 = pk2(0.f, 0.f);
    float s = 0.0f, aox = 0.f, aoy = 0.f, aoz = 0.f, aow = 0.f;

#pragma unroll 2
    for (int pl = 0; pl < 64; ++pl) {
        const int ploc = wv * 64 + pl;
        const half2t* rowq = (const half2t*)(reg0 + ploc * 96) + hl * 4;

        H8 bf1, bf2;
#pragma unroll
        for (int q = 0; q < 4; ++q) {
            bf1.h2[q] = __builtin_elementwise_max(anh1.h2[q] + rowq[q],     zero2);
            bf2.h2[q] = __builtin_elementwise_max(anh2.h2[q] + rowq[8 + q], zero2);
        }

        floatx16 zc = {};
        floatx16 acc = __builtin_amdgcn_mfma_f32_32x32x16_f16(af1.v, bf1.v, zc, 0, 0, 0);
        acc = __builtin_amdgcn_mfma_f32_32x32x16_f16(af2.v, bf2.v, acc, 0, 0, 0);

        float d0, d1, d2, d3;
        {
            half2t z0 = __builtin_elementwise_max(pk2(acc[0],  acc[1]),  zero2);
            half2t z1 = __builtin_elementwise_max(pk2(acc[2],  acc[3]),  zero2);
            half2t z2 = __builtin_elementwise_max(pk2(acc[4],  acc[5]),  zero2);
            half2t z3 = __builtin_elementwise_max(pk2(acc[6],  acc[7]),  zero2);
            half2t z4 = __builtin_elementwise_max(pk2(acc[8],  acc[9]),  zero2);
            half2t z5 = __builtin_elementwise_max(pk2(acc[10], acc[11]), zero2);
            half2t z6 = __builtin_elementwise_max(pk2(acc[12], acc[13]), zero2);
            half2t z7 = __builtin_elementwise_max(pk2(acc[14], acc[15]), zero2);
            d0 = __builtin_amdgcn_fdot2(z1, w3h[1], __builtin_amdgcn_fdot2(z0, w3h[0], 0.f, false), false);
            d1 = __builtin_amdgcn_fdot2(z3, w3h[3], __builtin_amdgcn_fdot2(z2, w3h[2], 0.f, false), false);
            d2 = __builtin_amdgcn_fdot2(z5, w3h[5], __builtin_amdgcn_fdot2(z4, w3h[4], 0.f, false), false);
            d3 = __builtin_amdgcn_fdot2(z7, w3h[7], __builtin_amdgcn_fdot2(z6, w3h[6], 0.f, false), false);
        }
        float dot = (d0 + d1) + (d2 + d3);
        dot += __shfl_xor(dot, 32);

        const float e = __expf(dot);   // logits ~N(0,1.3): no-max-sub safe
        const float4 cyv = cyS[ploc];
        s   += e;
        aox += e * cyv.x;
        aoy += e * cyv.y;
        aoz += e * cyv.z;
        aow += e * cyv.w;
    }

    // -------- post-p-loop cold-HBM register prefetch (phase B/C weights).
    // Issued here so latency hides under sA-write + 2 barriers + softmax
    // reduce + phase B; no live range crosses the p-loop. --------
    const int jcol = (wv << 5) + j32;
    const int nB = tid & 31;
    const int iB = tid >> 5;             // 0..15

    float wg2p[32];                      // GEMM2 first K-batch (q=0..3)
#pragma unroll
    for (int q = 0; q < 4; ++q)
#pragma unroll
        for (int t = 0; t < 4; ++t) {
            const int kb = q*16 + hl*8 + 2*t;
            wg2p[q*8 + 2*t]     = Wg2[kb*256 + jcol];
            wg2p[q*8 + 2*t + 1] = Wg2[(kb+1)*256 + jcol];
        }
    float wg1f[8], wg1g[8];
    const float bg1v = bg1[jcol];
#pragma unroll
    for (int q = 0; q < 4; ++q) {
        wg1f[2*q]   = Wg1[(k0g + 2*q)*256 + jcol];
        wg1f[2*q+1] = Wg1[(k0g + 2*q + 1)*256 + jcol];
        wg1g[2*q]   = Wg1[(16 + 2*q)*256 + jcol];
        wg1g[2*q+1] = Wg1[(17 + 2*q)*256 + jcol];
    }
    float xpre = 0.f;
    if (tid < 256) {
        const int nn = tid >> 3, k = tid & 7;
        xpre = (k < 4) ? r[(n0+nn)*4 + k] : rp[(n0+nn)*4 + k - 4];
    }
    float wpb[2], wpA[2][4];
#pragma unroll
    for (int rep = 0; rep < 2; ++rep) {
        const int i = iB + rep*16;
        wpb[rep]    = bp1[i];
        wpA[rep][0] = Wp1[i];
        wpA[rep][1] = Wp1[32 + i];
        wpA[rep][2] = Wp1[64 + i];
        wpA[rep][3] = Wp1[96 + i];
    }
    const float bp2v = bp2[iB];
    const float bg2v = bg2[jcol];
    const float w3vv = Wg3[jcol];
    const float bg3v = bg3[0];

    if (lane < 32) {
        sA[wv][lane]      = s;
        aoA[0][wv][lane]  = aox;
        aoA[1][wv][lane]  = aoy;
        aoA[2][wv][lane]  = aoz;
        aoA[3][wv][lane]  = aow;
    }
    __syncthreads();

    if (tid < 32) {
        float S = 0.f, A0 = 0.f, A1 = 0.f, A2 = 0.f, A3 = 0.f;
#pragma unroll
        for (int w = 0; w < 8; ++w) {
            S  += sA[w][tid];
            A0 += aoA[0][w][tid];
            A1 += aoA[1][w][tid];
            A2 += aoA[2][w][tid];
            A3 += aoA[3][w][tid];
        }
        const float inv = 1.0f / S;
        aoS[tid][0] = A0 * inv;
        aoS[tid][1] = A1 * inv;
        aoS[tid][2] = A2 * inv;
        aoS[tid][3] = A3 * inv;
    }
    __syncthreads();

    // ================= Phase B: c-MLP + x assembly =================
    float* hpS = (float*)(reg0 + HP_OFF);
    float* xS  = (float*)(reg0 + XS_OFF);

    if (tid < 256) {
        const int nn = tid >> 3, k = tid & 7;
        xS[nn*25 + k] = xpre;
    }
    {
        const float a0 = aoS[nB][0], a1 = aoS[nB][1], a2 = aoS[nB][2], a3 = aoS[nB][3];
#pragma unroll
        for (int rep = 0; rep < 2; ++rep) {
            const int i = iB + rep*16;
            float a = wpb[rep] + a0*wpA[rep][0] + a1*wpA[rep][1]
                               + a2*wpA[rep][2] + a3*wpA[rep][3];
            hpS[nB*33 + i] = fmaxf(a, 0.0f);
        }
    }
    __syncthreads();

    {
        float a = bp2v;
#pragma unroll
        for (int i = 0; i < 32; ++i) a += hpS[nB*33 + i] * Wp2[i*16 + iB];
        xS[nB*25 + 8 + iB] = a;
    }
    __syncthreads();

    // ================= Phase C: g-network via MFMA =================
    __fp16* g1S = (__fp16*)reg0;

    // GEMM1: g1 = relu(x @ Wg1 + bg1), K=24 padded to 32
    {
        H8 xa1, xa2, wb1, wb2;
        const float* xrow = xS + j32 * 25;
#pragma unroll
        for (int q = 0; q < 4; ++q) {
            xa1.h2[q] = pk2(xrow[k0g + 2*q], xrow[k0g + 2*q + 1]);
            wb1.h2[q] = pk2(wg1f[2*q], wg1f[2*q+1]);
            if (hl == 0) {
                xa2.h2[q] = pk2(xrow[16 + 2*q], xrow[16 + 2*q + 1]);
                wb2.h2[q] = pk2(wg1g[2*q], wg1g[2*q+1]);
            } else {
                xa2.h2[q] = pk2(0.f, 0.f);
                wb2.h2[q] = pk2(0.f, 0.f);
            }
        }
        floatx16 g1acc = {};
        g1acc = __builtin_amdgcn_mfma_f32_32x32x16_f16(xa1.v, wb1.v, g1acc, 0, 0, 0);
        g1acc = __builtin_amdgcn_mfma_f32_32x32x16_f16(xa2.v, wb2.v, g1acc, 0, 0, 0);

#pragma unroll
        for (int i = 0; i < 16; ++i) {
            const int row = (i & 3) + 8*(i >> 2) + 4*hl;
            g1S[row*264 + jcol] = (__fp16)fmaxf(g1acc[i] + bg1v, 0.0f);
        }
    }
    __syncthreads();

    // GEMM2: g2 = relu(g1 @ Wg2 + bg2); dot Wg3; exp.
    // First K-batch from register prefetch; later batches double-buffered.
    {
        floatx16 acc2 = {};
        const __fp16* arow = g1S + j32 * 264;

        H8 wB[4], wBn[4];
#pragma unroll
        for (int q = 0; q < 4; ++q)
#pragma unroll
            for (int t = 0; t < 4; ++t)
                wB[q].h2[t] = pk2(wg2p[q*8 + 2*t], wg2p[q*8 + 2*t + 1]);

#pragma unroll
        for (int c = 0; c < 4; ++c) {
            if (c < 3) {
#pragma unroll
                for (int q = 0; q < 4; ++q) {
                    const int kb = (c*4 + 4 + q)*16 + hl*8;
#pragma unroll
                    for (int t = 0; t < 4; ++t)
                        wBn[q].h2[t] = pk2(Wg2[(kb + 2*t)*256 + jcol],
                                           Wg2[(kb + 2*t + 1)*256 + jcol]);
                }
            }
#pragma unroll
            for (int q = 0; q < 4; ++q) {
                H8 af;
                af.v = *(const half8*)(arow + (c*4 + q)*16 + hl*8);
                acc2 = __builtin_amdgcn_mfma_f32_32x32x16_f16(af.v, wB[q].v, acc2, 0, 0, 0);
            }
#pragma unroll
            for (int q = 0; q < 4; ++q) wB[q] = wBn[q];
        }

        float part[16];
#pragma unroll
        for (int i = 0; i < 16; ++i)
            part[i] = fmaxf(acc2[i] + bg2v, 0.0f) * w3vv;
#pragma unroll
        for (int off = 1; off <= 16; off <<= 1) {
#pragma unroll
            for (int i = 0; i < 16; ++i) part[i] += __shfl_xor(part[i], off);
        }
        float* redS = &sA[0][0];
        if ((lane & 31) == 0) {
#pragma unroll
            for (int i = 0; i < 16; ++i) {
                const int row = (i & 3) + 8*(i >> 2) + 4*hl;
                redS[wv*32 + row] = part[i];
            }
        }
        __syncthreads();

        if (tid < 32) {
            float v = bg3v;
#pragma unroll
            for (int w = 0; w < 8; ++w) v += redS[w*32 + tid];
            out[n0 + tid] = __expf(v);
        }
    }
}

extern "C" void kernel_launch(void* const* d_in, const int* in_sizes, int n_in,
                              void* d_out, int out_size, void* d_ws, size_t ws_size,
                              hipStream_t stream)
{
    const float* r   = (const float*)d_in[0];
    const float* rp  = (const float*)d_in[1];
    const float* cx  = (const float*)d_in[2];
    const float* cy  = (const float*)d_in[3];
    const float* Wa1 = (const float*)d_in[4];
    const float* Wa2 = (const float*)d_in[5];
    const float* Wa3 = (const float*)d_in[6];
    const float* Wp1 = (const float*)d_in[7];
    const float* bp1 = (const float*)d_in[8];
    const float* Wp2 = (const float*)d_in[9];
    const float* bp2 = (const float*)d_in[10];
    const float* Wg1 = (const float*)d_in[11];
    const float* bg1 = (const float*)d_in[12];
    const float* Wg2 = (const float*)d_in[13];
    const float* bg2 = (const float*)d_in[14];
    const float* Wg3 = (const float*)d_in[15];
    const float* bg3 = (const float*)d_in[16];

    hipLaunchKernelGGL(k_fused, dim3(N_/32), dim3(512), 0, stream,
                       r, rp, cx, cy, Wa1, Wa2, Wa3, Wp1, bp1, Wp2, bp2,
                       Wg1, bg1, Wg2, bg2, Wg3, bg3, (float*)d_out);
}